// Round 18
// baseline (158.288 us; speedup 1.0000x reference)
//
#include <hip/hip_runtime.h>
#include <cstdint>
#include <cstddef>

#define CIN     16
#define CHID    16
#define T_DIM   31
#define HW_     16384            // 128*128
#define CH_STRIDE 507904         // 31*128*128
#define TILE_H  8
#define TILE_W  32
#define SH      10               // TILE_H + 2
#define SW      34               // TILE_W + 2
#define SPOS    (SH * SW)        // 340 positions
#define PSTR    24               // 48B/position: 16B-aligned ds_read_b128
#define SLICE_SH (SPOS * PSTR)   // 8160 shorts = 16,320 B
#define NSLOT   4                // 65,280 B static LDS ring

typedef short bf16x8 __attribute__((ext_vector_type(8)));
typedef float f32x16 __attribute__((ext_vector_type(16)));

__device__ __forceinline__ unsigned bf16_bits(float x) {
  unsigned u = __builtin_bit_cast(unsigned, x);
  u += 0x7FFFu + ((u >> 16) & 1u);
  return u >> 16;
}
__device__ __forceinline__ unsigned cvt_pk_bf16(float lo, float hi) {
  unsigned r;
  asm("v_cvt_pk_bf16_f32 %0, %1, %2" : "=v"(r) : "v"(lo), "v"(hi));
  return r;
}

__global__ __launch_bounds__(512, 2)
void qrnn3d_v18(const float* __restrict__ in, const float* __restrict__ Wg,
                const float* __restrict__ bg, float* __restrict__ out) {
  __shared__ __align__(16) short xs[NSLOT][SLICE_SH];

  const int tid = threadIdx.x;
  const int bid = blockIdx.x;
  // bijective XCD-chunked swizzle (256 blocks, 256%8==0)
  const int lin  = ((bid & 7) << 5) | (bid >> 3);
  const int b    = lin >> 6;                 // 4 batches x 64 tiles
  const int tile = lin & 63;
  const int h0   = (tile >> 2) * TILE_H;     // 16 h-tiles
  const int w0   = (tile & 3) * TILE_W;      // 4 w-tiles

  const int lane = tid & 63;
  const int wid  = tid >> 6;                 // wave 0..7 -> output row
  const int col  = lane & 31;                // MFMA N column / oc for A-frag
  const int half = lane >> 5;                // K half (ci 0-7 / 8-15)

  // ---- weights -> 27 A-frags ----
  bf16x8 wfrag[27];
#pragma unroll
  for (int tau = 0; tau < 27; ++tau) {
    bf16x8 f;
#pragma unroll
    for (int j = 0; j < 8; ++j)
      f[j] = (short)bf16_bits(Wg[col * 432 + (half * 8 + j) * 27 + tau]);
    wfrag[tau] = f;
  }

  // ---- bias-preloaded accumulator template + t-invariant store offsets ----
  f32x16 accInit;
  int voff[8];
#pragma unroll
  for (int r = 0; r < 8; ++r) {
    int oc = (r & 3) + 8 * (r >> 2) + 4 * half;          // 0..15
    accInit[r]     = bg[oc];
    accInit[r + 8] = bg[oc + 16];
    voff[r] = (b * CHID + oc) * CH_STRIDE + (h0 + wid) * 128 + (w0 + col);
  }

  // ---- staging precompute (t-invariant): unit = (pos, ci-quad), 3/thread ----
  const float* gp[3];
  int  lso[3];
  bool stv[3], ldv[3];
#pragma unroll
  for (int i = 0; i < 3; ++i) {
    int p   = tid + i * 512;         // [0,1536) covers 340*4=1360 units
    int q   = p & 15;
    int c4  = (p >> 4) & 3;
    int j   = p >> 6;
    int pos = j * 16 + q;            // [0,384)
    stv[i]  = (pos < SPOS);
    int hh  = pos / SW;
    int ww  = pos - hh * SW;
    int gh  = h0 + hh - 1, gw = w0 + ww - 1;
    ldv[i]  = stv[i] && ((unsigned)gh < 128u) && ((unsigned)gw < 128u);
    int sp  = ldv[i] ? (gh * 128 + gw) : 0;
    gp[i]   = in + (size_t)(b * CIN + c4 * 4) * CH_STRIDE + sp;
    lso[i]  = pos * PSTR + c4 * 4;   // shorts
  }

#define LOADV(tz, vv)                                                \
  do {                                                               \
    if ((tz) <= 30) {                                                \
      const int toff = (tz) * HW_;                                   \
      _Pragma("unroll")                                              \
      for (int i = 0; i < 3; ++i) {                                  \
        _Pragma("unroll")                                            \
        for (int k = 0; k < 4; ++k)                                  \
          vv[i][k] = ldv[i] ? gp[i][toff + k * CH_STRIDE] : 0.0f;    \
      }                                                              \
    } else {                                                         \
      _Pragma("unroll")                                              \
      for (int i = 0; i < 3; ++i) {                                  \
        _Pragma("unroll")                                            \
        for (int k = 0; k < 4; ++k) vv[i][k] = 0.0f;                 \
      }                                                              \
    }                                                                \
  } while (0)

#define STOREV(vv, slot)                                             \
  do {                                                               \
    short* dst = &xs[(slot)][0];                                     \
    _Pragma("unroll")                                                \
    for (int i = 0; i < 3; ++i) {                                    \
      if (stv[i]) {                                                  \
        uint2 u;                                                     \
        u.x = cvt_pk_bf16(vv[i][0], vv[i][1]);                       \
        u.y = cvt_pk_bf16(vv[i][2], vv[i][3]);                       \
        *reinterpret_cast<uint2*>(dst + lso[i]) = u;                 \
      }                                                              \
    }                                                                \
  } while (0)

  // ---- compute geometry: 9 LDS read offsets (kh,kw), t-invariant ----
  int lb[9];
#pragma unroll
  for (int kh = 0; kh < 3; ++kh)
#pragma unroll
    for (int kw = 0; kw < 3; ++kw)
      lb[kh * 3 + kw] = ((wid + kh) * SW + (col + kw)) * PSTR + half * 8;

  float hst[8];
#pragma unroll
  for (int r = 0; r < 8; ++r) hst[r] = 0.0f;

  const float C_TANH = 2.8853900817779268f;   // 2*log2(e)
  const float C_SIG  = 1.4426950408889634f;   // log2(e)

  // carr = frags of slice t (read last step); fresh <- frags of slice t+1
  // (fresh becomes next step's carr). kd0 (slice t-1) re-read as transients.
  auto computeC = [&](int t, bf16x8 (&carr)[9], bf16x8 (&fresh)[9]) {
    const short* base = &xs[0][0];
    const short* s0 = base + ((t + 3) & 3) * SLICE_SH;   // slice t-1
    const short* s2 = base + ((t + 1) & 3) * SLICE_SH;   // slice t+1

    // fresh reads issued first (land while kd1 MFMAs run from registers)
#pragma unroll
    for (int u = 0; u < 9; ++u)
      fresh[u] = *reinterpret_cast<const bf16x8*>(s2 + lb[u]);

    f32x16 acc0 = accInit;
    f32x16 acc1;
#pragma unroll
    for (int i = 0; i < 16; ++i) acc1[i] = 0.0f;

    // kd=1: operands already in registers -> zero LDS wait
#pragma unroll
    for (int u = 0; u < 9; ++u) {
      const int tau = 9 + u;
      if (tau & 1)
        acc1 = __builtin_amdgcn_mfma_f32_32x32x16_bf16(wfrag[tau], carr[u], acc1, 0, 0, 0);
      else
        acc0 = __builtin_amdgcn_mfma_f32_32x32x16_bf16(wfrag[tau], carr[u], acc0, 0, 0, 0);
    }
    // kd=0: transient re-reads, paired read->MFMA to bound liveness
#pragma unroll
    for (int u = 0; u < 9; ++u) {
      bf16x8 xb = *reinterpret_cast<const bf16x8*>(s0 + lb[u]);
      if (u & 1)
        acc1 = __builtin_amdgcn_mfma_f32_32x32x16_bf16(wfrag[u], xb, acc1, 0, 0, 0);
      else
        acc0 = __builtin_amdgcn_mfma_f32_32x32x16_bf16(wfrag[u], xb, acc0, 0, 0, 0);
    }
    // kd=2: from fresh
#pragma unroll
    for (int u = 0; u < 9; ++u) {
      const int tau = 18 + u;
      if (tau & 1)
        acc1 = __builtin_amdgcn_mfma_f32_32x32x16_bf16(wfrag[tau], fresh[u], acc1, 0, 0, 0);
      else
        acc0 = __builtin_amdgcn_mfma_f32_32x32x16_bf16(wfrag[tau], fresh[u], acc0, 0, 0, 0);
    }

    float* outT = out + (size_t)t * HW_;
#pragma unroll
    for (int r = 0; r < 8; ++r) {
      float zg = acc0[r] + acc1[r];
      float fg = acc0[r + 8] + acc1[r + 8];
      float ez = exp2f(zg * C_TANH);
      float z  = __builtin_fmaf(-2.0f, __builtin_amdgcn_rcpf(ez + 1.0f), 1.0f);
      float ef = exp2f(-fg * C_SIG);
      float f  = __builtin_amdgcn_rcpf(1.0f + ef);
      float h  = __builtin_fmaf(f, hst[r] - z, z);
      hst[r]   = h;
      outT[voff[r]] = h;
    }
  };

  // ---- prologue: slices 0,1 staged; slice 2 in regs; slot3 = zeros (slice -1)
  float vA[3][4], vB[3][4];
  LOADV(0, vA); STOREV(vA, 0);
  LOADV(1, vA); STOREV(vA, 1);
  LOADV(2, vA);
  for (int i = tid; i < SLICE_SH / 2; i += 512)
    reinterpret_cast<unsigned*>(&xs[3][0])[i] = 0u;
  __syncthreads();

  // pre-read carried frags = slice 0 (slot 0) for step 0's kd=1
  bf16x8 xfA[9], xfB[9];
#pragma unroll
  for (int u = 0; u < 9; ++u)
    xfA[u] = *reinterpret_cast<const bf16x8*>(&xs[0][0] + lb[u]);

#pragma unroll 1
  for (int t = 0; t < 30; t += 2) {
    // even step: regs A hold slice t+2; carried = xfA (slice t)
    LOADV(t + 3, vB);
    STOREV(vA, (t + 2) & 3);
    computeC(t, xfA, xfB);            // fresh -> xfB (slice t+1)
    __syncthreads();
    // odd step: regs B hold slice t+3; carried = xfB (slice t+1)
    LOADV(t + 4, vA);
    STOREV(vB, (t + 3) & 3);
    computeC(t + 1, xfB, xfA);        // fresh -> xfA (slice t+2)
    __syncthreads();
  }
  // tail t=30: carried = xfA (slice 30); kd2 fresh-reads slot 3 (zeros)
  computeC(30, xfA, xfB);

#undef LOADV
#undef STOREV
}

extern "C" void kernel_launch(void* const* d_in, const int* in_sizes, int n_in,
                              void* d_out, int out_size, void* d_ws, size_t ws_size,
                              hipStream_t stream) {
  const float* in = (const float*)d_in[0];
  const float* Wg = (const float*)d_in[1];
  const float* bg = (const float*)d_in[2];
  float* out      = (float*)d_out;
  (void)in_sizes; (void)n_in; (void)out_size; (void)d_ws; (void)ws_size;
  qrnn3d_v18<<<dim3(256), dim3(512), 0, stream>>>(in, Wg, bg, out);
}

// Round 19
// 120.075 us; speedup vs baseline: 1.3182x; 1.3182x over previous
//
#include <hip/hip_runtime.h>
#include <cstdint>
#include <cstddef>

#define CIN     16
#define CHID    16
#define T_DIM   31
#define HW_     16384            // 128*128
#define CH_STRIDE 507904         // 31*128*128
#define TILE_H  8
#define TILE_W  32
#define SH      10               // TILE_H + 2
#define SW      34               // TILE_W + 2
#define SPOS    (SH * SW)        // 340 positions
#define PSTR    24               // 48B/position: 16B-aligned ds_read_b128 (PSTR=20 costs 2x — R6/R8/R10)
#define SLICE_SH (SPOS * PSTR)   // 8160 shorts = 16,320 B
#define NSLOT   4                // 65,280 B LDS ring (< 64 KiB static limit)

typedef short bf16x8 __attribute__((ext_vector_type(8)));
typedef float f32x16 __attribute__((ext_vector_type(16)));

__device__ __forceinline__ unsigned bf16_bits(float x) {
  unsigned u = __builtin_bit_cast(unsigned, x);
  u += 0x7FFFu + ((u >> 16) & 1u);
  return u >> 16;
}
__device__ __forceinline__ unsigned cvt_pk_bf16(float lo, float hi) {
  unsigned r;
  asm("v_cvt_pk_bf16_f32 %0, %1, %2" : "=v"(r) : "v"(lo), "v"(hi));
  return r;
}

__global__ __launch_bounds__(512, 2)
void qrnn3d_v19(const float* __restrict__ in, const float* __restrict__ Wg,
                const float* __restrict__ bg, float* __restrict__ out) {
  __shared__ __align__(16) short xs[NSLOT][SLICE_SH];

  const int tid = threadIdx.x;
  const int bid = blockIdx.x;
  // bijective XCD-chunked swizzle (256 blocks, 256%8==0): XCD k gets 32
  // consecutive lin = 8 contiguous h-tiles x 4 w-tiles -> halo L2 sharing
  const int lin  = ((bid & 7) << 5) | (bid >> 3);
  const int b    = lin >> 6;                 // 4 batches x 64 tiles
  const int tile = lin & 63;
  const int h0   = (tile >> 2) * TILE_H;     // 16 h-tiles
  const int w0   = (tile & 3) * TILE_W;      // 4 w-tiles

  const int lane = tid & 63;
  const int wid  = tid >> 6;                 // wave 0..7 -> output row
  const int col  = lane & 31;                // MFMA N column / oc for A-frag
  const int half = lane >> 5;                // K half (ci 0-7 / 8-15)

  // ---- weights -> 27 A-frags ----
  bf16x8 wfrag[27];
#pragma unroll
  for (int tau = 0; tau < 27; ++tau) {
    bf16x8 f;
#pragma unroll
    for (int j = 0; j < 8; ++j)
      f[j] = (short)bf16_bits(Wg[col * 432 + (half * 8 + j) * 27 + tau]);
    wfrag[tau] = f;
  }

  // ---- bias-preloaded accumulator template + t-invariant store offsets ----
  f32x16 accInit;
  int voff[8];
#pragma unroll
  for (int r = 0; r < 8; ++r) {
    int oc = (r & 3) + 8 * (r >> 2) + 4 * half;          // 0..15
    accInit[r]     = bg[oc];
    accInit[r + 8] = bg[oc + 16];
    voff[r] = (b * CHID + oc) * CH_STRIDE + (h0 + wid) * 128 + (w0 + col);
  }

  // ---- staging precompute (t-invariant): unit = (pos, ci-quad), 3/thread ----
  const float* gp[3];
  int  lso[3];
  bool stv[3], ldv[3];
#pragma unroll
  for (int i = 0; i < 3; ++i) {
    int p   = tid + i * 512;         // [0,1536) covers 340*4=1360 units
    int q   = p & 15;
    int c4  = (p >> 4) & 3;
    int j   = p >> 6;
    int pos = j * 16 + q;            // [0,384)
    stv[i]  = (pos < SPOS);
    int hh  = pos / SW;
    int ww  = pos - hh * SW;
    int gh  = h0 + hh - 1, gw = w0 + ww - 1;
    ldv[i]  = stv[i] && ((unsigned)gh < 128u) && ((unsigned)gw < 128u);
    int sp  = ldv[i] ? (gh * 128 + gw) : 0;
    gp[i]   = in + (size_t)(b * CIN + c4 * 4) * CH_STRIDE + sp;
    lso[i]  = pos * PSTR + c4 * 4;   // shorts
  }

#define LOADV(tz, vv)                                                \
  do {                                                               \
    if ((tz) <= 30) {                                                \
      const int toff = (tz) * HW_;                                   \
      _Pragma("unroll")                                              \
      for (int i = 0; i < 3; ++i) {                                  \
        _Pragma("unroll")                                            \
        for (int k = 0; k < 4; ++k)                                  \
          vv[i][k] = ldv[i] ? gp[i][toff + k * CH_STRIDE] : 0.0f;    \
      }                                                              \
    } else {                                                         \
      _Pragma("unroll")                                              \
      for (int i = 0; i < 3; ++i) {                                  \
        _Pragma("unroll")                                            \
        for (int k = 0; k < 4; ++k) vv[i][k] = 0.0f;                 \
      }                                                              \
    }                                                                \
  } while (0)

#define STOREV(vv, slot)                                             \
  do {                                                               \
    short* dst = &xs[(slot)][0];                                     \
    _Pragma("unroll")                                                \
    for (int i = 0; i < 3; ++i) {                                    \
      if (stv[i]) {                                                  \
        uint2 u;                                                     \
        u.x = cvt_pk_bf16(vv[i][0], vv[i][1]);                       \
        u.y = cvt_pk_bf16(vv[i][2], vv[i][3]);                       \
        *reinterpret_cast<uint2*>(dst + lso[i]) = u;                 \
      }                                                              \
    }                                                                \
  } while (0)

  // ---- compute geometry: 9 LDS read offsets (kh,kw), t-invariant ----
  int lb[9];
#pragma unroll
  for (int kh = 0; kh < 3; ++kh)
#pragma unroll
    for (int kw = 0; kw < 3; ++kw)
      lb[kh * 3 + kw] = ((wid + kh) * SW + (col + kw)) * PSTR + half * 8;

  float hst[8];
#pragma unroll
  for (int r = 0; r < 8; ++r) hst[r] = 0.0f;

  const float C_TANH = 2.8853900817779268f;   // 2*log2(e)
  const float C_SIG  = 1.4426950408889634f;   // log2(e)

  auto compute = [&](int t) {
    const short* base = &xs[0][0];
    const short* sA = base + ((t + 3) & 3) * SLICE_SH;   // slice t-1
    const short* sB = base + ((t    ) & 3) * SLICE_SH;   // slice t
    const short* sC = base + ((t + 1) & 3) * SLICE_SH;   // slice t+1

    f32x16 acc0 = accInit;
    f32x16 acc1;
#pragma unroll
    for (int i = 0; i < 16; ++i) acc1[i] = 0.0f;

#pragma unroll
    for (int kd = 0; kd < 3; ++kd) {
      const short* sp = (kd == 0) ? sA : (kd == 1) ? sB : sC;
#pragma unroll
      for (int u = 0; u < 9; ++u) {
        const int tau = kd * 9 + u;
        bf16x8 xb = *reinterpret_cast<const bf16x8*>(sp + lb[u]);
        if (tau & 1)
          acc1 = __builtin_amdgcn_mfma_f32_32x32x16_bf16(wfrag[tau], xb, acc1, 0, 0, 0);
        else
          acc0 = __builtin_amdgcn_mfma_f32_32x32x16_bf16(wfrag[tau], xb, acc0, 0, 0, 0);
      }
    }

    float* outT = out + (size_t)t * HW_;
#pragma unroll
    for (int r = 0; r < 8; ++r) {
      float zg = acc0[r] + acc1[r];
      float fg = acc0[r + 8] + acc1[r + 8];
      float ez = exp2f(zg * C_TANH);
      float z  = __builtin_fmaf(-2.0f, __builtin_amdgcn_rcpf(ez + 1.0f), 1.0f);
      float ef = exp2f(-fg * C_SIG);
      float f  = __builtin_amdgcn_rcpf(1.0f + ef);
      float h  = __builtin_fmaf(f, hst[r] - z, z);
      hst[r]   = h;
      outT[voff[r]] = h;
    }
  };

  // ---- prologue: slices 0,1 staged; slice 2 in regs; slot3 = zeros (slice -1)
  float vA[3][4], vB[3][4];
  LOADV(0, vA); STOREV(vA, 0);
  LOADV(1, vA); STOREV(vA, 1);
  LOADV(2, vA);
  for (int i = tid; i < SLICE_SH / 2; i += 512)
    reinterpret_cast<unsigned*>(&xs[3][0])[i] = 0u;
  __syncthreads();

#pragma unroll 1
  for (int t = 0; t < 30; t += 2) {
    // even step: regs A hold slice t+2
    LOADV(t + 3, vB);                 // issue loads early
    STOREV(vA, (t + 2) & 3);
    compute(t);
    __syncthreads();
    // odd step: regs B hold slice t+3
    LOADV(t + 4, vA);
    STOREV(vB, (t + 3) & 3);
    compute(t + 1);
    __syncthreads();
  }
  compute(30);

#undef LOADV
#undef STOREV
}

extern "C" void kernel_launch(void* const* d_in, const int* in_sizes, int n_in,
                              void* d_out, int out_size, void* d_ws, size_t ws_size,
                              hipStream_t stream) {
  const float* in = (const float*)d_in[0];
  const float* Wg = (const float*)d_in[1];
  const float* bg = (const float*)d_in[2];
  float* out      = (float*)d_out;
  (void)in_sizes; (void)n_in; (void)out_size; (void)d_ws; (void)ws_size;
  qrnn3d_v19<<<dim3(256), dim3(512), 0, stream>>>(in, Wg, bg, out);
}